// Round 5
// baseline (4308.884 us; speedup 1.0000x reference)
//
#include <hip/hip_runtime.h>
#include <stdint.h>

typedef unsigned long long u64;
typedef unsigned int u32;
using short8  = __attribute__((ext_vector_type(8))) short;
using f32x16  = __attribute__((ext_vector_type(16))) float;

__constant__ int c_LN[5]   = {76800, 19200, 4800, 1200, 300}; // H*H*3 per level
__constant__ int c_LOFF[5] = {0, 76800, 96000, 100800, 102000};
__constant__ int c_KK[5]   = {1000, 1000, 1000, 1000, 300};   // k1 = min(1000, N)

#define TOT_PL 102300
#define BBCLIP 4.1351665567423560f

__device__ __forceinline__ u32 fkey(float f) {
  u32 b = __float_as_uint(f);
  return b ^ (u32)(((int)b >> 31) | 0x80000000u);
}

template<int NELEM>
__device__ __forceinline__ void bitonic_desc(u64* sb, int t) {
  constexpr int PAIRS = NELEM / 2;
  for (int size = 2; size <= NELEM; size <<= 1) {
    for (int stride = size >> 1; stride > 0; stride >>= 1) {
      __syncthreads();
      for (int i = t; i < PAIRS; i += 256) {
        int pos = 2 * i - (i & (stride - 1));
        u64 a = sb[pos], b = sb[pos + stride];
        bool desc = ((pos & size) == 0);
        if (desc ? (a < b) : (a > b)) { sb[pos] = b; sb[pos + stride] = a; }
      }
    }
  }
  __syncthreads();
}

// ---------------- K0: pre-transpose weights, 3-way bf16 split ----------------
// chunk ca = tap*16 + g covers k [16ca,16ca+16): ci = g*16 + kloc, kloc = half*8 + j.
// Wt u16 layout: slice = (ca*6 + split*2 + half); within slice: co granule of 8 u16.
__global__ __launch_bounds__(256) void prep_weights(
    const float* __restrict__ Wf, unsigned short* __restrict__ Wt)
{
  int idx = blockIdx.x * 256 + threadIdx.x;   // E = 2304*256
  if (idx >= 589824) return;
  int co = idx & 255;
  int k2 = idx >> 8;            // 0..2303
  int chunk = k2 >> 4, kloc = k2 & 15;
  int tap = chunk / 16, g = chunk & 15;
  int ci = (g << 4) + kloc;
  float v = Wf[co * 2304 + ci * 9 + tap];
  u32 u0 = __float_as_uint(v) & 0xFFFF0000u;
  float r1 = v - __uint_as_float(u0);
  u32 u1 = __float_as_uint(r1) & 0xFFFF0000u;
  float r2 = r1 - __uint_as_float(u1);
  u32 u2 = __float_as_uint(r2) & 0xFFFF0000u;
  int half = kloc >> 3, j = kloc & 7;
  int base = (chunk * 6 + half) * 2048 + co * 8 + j;   // +4096 u16 per split
  Wt[base]          = (unsigned short)(u0 >> 16);
  Wt[base + 4096]   = (unsigned short)(u1 >> 16);
  Wt[base + 8192]   = (unsigned short)(u2 >> 16);
}

// ---------------- K1: 3x3 conv via MFMA, halo-staged, split-once ----------------
// tile 128co x 128px (8 rows x 16 cols), 4 waves 2x2 of 64x64.
// Per ci-block (16 ch): load 10x18 fp32 halo once, split+pack once into bf16-pair
// planes, then 9 taps read B-frags directly from LDS; A-frags direct from global Wt.
__global__ __launch_bounds__(256, 3) void conv_mfma(
    const float* __restrict__ feat, const u32* __restrict__ Wt32,
    const float* __restrict__ bf, float* __restrict__ out0,
    int H, int W, int tiles_x, int S, int pstride, int fuse)
{
  __shared__ float fhalo[3200];      // [ci16][y10][x20]  12.8 KB
  __shared__ u32   haloPf[4800];     // [sp3][pair8][y10][x20] 19.2 KB
  const int t  = threadIdx.x;
  const int HW = H * W;
  const int tile = blockIdx.x;
  const int tx = tile % tiles_x, ty = tile / tiles_x;
  const int c0 = tx * 16, r0 = ty * 8;
  const int cob = blockIdx.y * 128;
  const int bz = blockIdx.z;
  const int n = bz / S, s = bz - n * S;
  const int gcount = 16 / S, g0 = s * gcount;
  const float* featN = feat + (size_t)n * 256 * HW;
  const uint4* Wtq = (const uint4*)Wt32;

  const int lane = t & 63;
  const int wave = t >> 6;
  const int wy = wave >> 1, wx = wave & 1;
  const int fh = lane >> 5;          // frag k-half
  const int ln31 = lane & 31;

  f32x16 acc[2][2];
#pragma unroll
  for (int i = 0; i < 2; i++)
#pragma unroll
    for (int j = 0; j < 2; j++)
#pragma unroll
      for (int e = 0; e < 16; e++) acc[i][j][e] = 0.f;

  for (int gl = 0; gl < gcount; gl++) {
    const int g = g0 + gl;
    __syncthreads();   // previous iteration's readers done before overwrite
    // ---- phase 1: fp32 halo load (16 ci x 10 y x 18 x, x-padded to 20) ----
    {
      const float* fc = featN + (size_t)(g << 4) * HW;
#pragma unroll
      for (int i = 0; i < 13; i++) {
        int e = t + i * 256;
        if (e < 3200) {
          int ci = e / 200, rem = e - ci * 200;
          int y = rem / 20, x = rem - y * 20;
          int gy = r0 + y - 1, gx = c0 + x - 1;
          float v = 0.f;
          if (x < 18 && (unsigned)gy < (unsigned)H && (unsigned)gx < (unsigned)W)
            v = fc[(size_t)ci * HW + gy * W + gx];
          fhalo[e] = v;
        }
      }
    }
    __syncthreads();
    // ---- phase 2: split 3-way + pack ci-pairs ----
    {
#pragma unroll
      for (int i = 0; i < 7; i++) {
        int e2 = t + i * 256;
        if (e2 < 1600) {
          int pr = e2 / 200, rem = e2 - pr * 200;
          float a = fhalo[(2 * pr) * 200 + rem];
          float b = fhalo[(2 * pr + 1) * 200 + rem];
          u32 a0 = __float_as_uint(a) & 0xFFFF0000u;
          float ar1 = a - __uint_as_float(a0);
          u32 a1 = __float_as_uint(ar1) & 0xFFFF0000u;
          float ar2 = ar1 - __uint_as_float(a1);
          u32 a2 = __float_as_uint(ar2) & 0xFFFF0000u;
          u32 b0 = __float_as_uint(b) & 0xFFFF0000u;
          float br1 = b - __uint_as_float(b0);
          u32 b1 = __float_as_uint(br1) & 0xFFFF0000u;
          float br2 = br1 - __uint_as_float(b1);
          u32 b2 = __float_as_uint(br2) & 0xFFFF0000u;
          haloPf[e2]        = (a0 >> 16) | b0;
          haloPf[e2 + 1600] = (a1 >> 16) | b1;
          haloPf[e2 + 3200] = (a2 >> 16) | b2;
        }
      }
    }
    __syncthreads();
    // ---- 9 taps, no barriers (haloPf read-only; A from global) ----
    for (int tap = 0; tap < 9; tap++) {
      const int ca = tap * 16 + g;
      // A frags: direct global loads (coalesced; L2-resident Wt)
      uint4 aQ[3][2];
#pragma unroll
      for (int sp = 0; sp < 3; sp++)
#pragma unroll
        for (int ti = 0; ti < 2; ti++)
          aQ[sp][ti] = Wtq[(size_t)(ca * 6 + sp * 2 + fh) * 256 + cob + wy * 64 + ti * 32 + ln31];
      // B frags: direct LDS reads from packed halo planes
      const int tdy = tap / 3, tdx = tap - tdy * 3;
      uint4 bQ[3][2];
#pragma unroll
      for (int tj = 0; tj < 2; tj++) {
        int px = wx * 64 + tj * 32 + ln31;
        int base = (px >> 4) * 20 + (px & 15) + tdy * 20 + tdx;
        int i0 = fh * 800 + base;
#pragma unroll
        for (int sp = 0; sp < 3; sp++) {
          bQ[sp][tj].x = haloPf[sp * 1600 + i0];
          bQ[sp][tj].y = haloPf[sp * 1600 + i0 + 200];
          bQ[sp][tj].z = haloPf[sp * 1600 + i0 + 400];
          bQ[sp][tj].w = haloPf[sp * 1600 + i0 + 600];
        }
      }
      short8 aT[3][2], bT[3][2];
#pragma unroll
      for (int sp = 0; sp < 3; sp++)
#pragma unroll
        for (int q = 0; q < 2; q++) {
          aT[sp][q] = *(short8*)&aQ[sp][q];
          bT[sp][q] = *(short8*)&bQ[sp][q];
        }
#pragma unroll
      for (int ti = 0; ti < 2; ti++)
#pragma unroll
        for (int tj = 0; tj < 2; tj++) {
          acc[ti][tj] = __builtin_amdgcn_mfma_f32_32x32x16_bf16(aT[1][ti], bT[1][tj], acc[ti][tj], 0, 0, 0);
          acc[ti][tj] = __builtin_amdgcn_mfma_f32_32x32x16_bf16(aT[0][ti], bT[2][tj], acc[ti][tj], 0, 0, 0);
          acc[ti][tj] = __builtin_amdgcn_mfma_f32_32x32x16_bf16(aT[2][ti], bT[0][tj], acc[ti][tj], 0, 0, 0);
          acc[ti][tj] = __builtin_amdgcn_mfma_f32_32x32x16_bf16(aT[0][ti], bT[1][tj], acc[ti][tj], 0, 0, 0);
          acc[ti][tj] = __builtin_amdgcn_mfma_f32_32x32x16_bf16(aT[1][ti], bT[0][tj], acc[ti][tj], 0, 0, 0);
          acc[ti][tj] = __builtin_amdgcn_mfma_f32_32x32x16_bf16(aT[0][ti], bT[0][tj], acc[ti][tj], 0, 0, 0);
        }
    }
  }

  // ---- epilogue ----
  float* outp = fuse ? out0 : (out0 + (size_t)s * pstride);
#pragma unroll
  for (int ti = 0; ti < 2; ti++)
#pragma unroll
    for (int tj = 0; tj < 2; tj++) {
      int pxo = wx * 64 + tj * 32 + ln31;
      int y = r0 + (pxo >> 4), x = c0 + (pxo & 15);
      if (y >= H || x >= W) continue;
#pragma unroll
      for (int reg = 0; reg < 16; reg++) {
        int row = (reg & 3) + 8 * (reg >> 2) + 4 * fh;
        int co = cob + wy * 64 + ti * 32 + row;
        float vv = acc[ti][tj][reg];
        if (fuse) vv = fmaxf(vv + bf[co], 0.f);
        outp[(size_t)(n * 256 + co) * HW + y * W + x] = vv;
      }
    }
}

// ---------------- K1b: sum split-K partials + bias + relu (deterministic order) ----------------
__global__ __launch_bounds__(256) void reduce_brelu(
    const float* __restrict__ partial, const float* __restrict__ bf,
    float* __restrict__ rf, int E, int HW, int S, int pstride)
{
  int idx = blockIdx.x * 256 + threadIdx.x;
  if (idx >= E) return;
  float sum = partial[idx];
  for (int sp = 1; sp < S; sp++) sum += partial[(size_t)sp * pstride + idx];
  int c = (idx / HW) & 255;
  rf[idx] = fmaxf(sum + bf[c], 0.f);
}

// ---------------- K2: 15-ch projection + sigmoid + decode + clip + filter ----------------
__global__ __launch_bounds__(256) void proj_decode(
    const float* __restrict__ rf, const float* __restrict__ Wsc,
    const float* __restrict__ bsc, const float* __restrict__ Wdl,
    const float* __restrict__ bdl, const float* __restrict__ imsh,
    float* __restrict__ probs, float* __restrict__ boxes,
    int H, int W, int lvl_off, float sstride, float asize)
{
  __shared__ float4 wall[256 * 4];
  const int t = threadIdx.x;
  {
    int c = t;
    wall[c * 4 + 0] = make_float4(Wsc[c], Wsc[256 + c], Wsc[512 + c], Wdl[c]);
    wall[c * 4 + 1] = make_float4(Wdl[256 + c], Wdl[512 + c], Wdl[768 + c], Wdl[1024 + c]);
    wall[c * 4 + 2] = make_float4(Wdl[1280 + c], Wdl[1536 + c], Wdl[1792 + c], Wdl[2048 + c]);
    wall[c * 4 + 3] = make_float4(Wdl[2304 + c], Wdl[2560 + c], Wdl[2816 + c], 0.f);
  }
  __syncthreads();
  const int HW = H * W;
  int idx = blockIdx.x * 256 + t;
  if (idx >= 2 * HW) return;
  int n  = idx / HW;
  int hw = idx - n * HW;
  const float* rp = rf + (size_t)n * 256 * HW + hw;
  float4 s0 = {0,0,0,0}, s1 = {0,0,0,0}, s2 = {0,0,0,0}, s3 = {0,0,0,0};
#pragma unroll 4
  for (int c = 0; c < 256; c++) {
    float v = rp[(size_t)c * HW];
    float4 w0 = wall[c*4+0], w1 = wall[c*4+1], w2 = wall[c*4+2], w3 = wall[c*4+3];
    s0.x = fmaf(v, w0.x, s0.x); s0.y = fmaf(v, w0.y, s0.y); s0.z = fmaf(v, w0.z, s0.z); s0.w = fmaf(v, w0.w, s0.w);
    s1.x = fmaf(v, w1.x, s1.x); s1.y = fmaf(v, w1.y, s1.y); s1.z = fmaf(v, w1.z, s1.z); s1.w = fmaf(v, w1.w, s1.w);
    s2.x = fmaf(v, w2.x, s2.x); s2.y = fmaf(v, w2.y, s2.y); s2.z = fmaf(v, w2.z, s2.z); s2.w = fmaf(v, w2.w, s2.w);
    s3.x = fmaf(v, w3.x, s3.x); s3.y = fmaf(v, w3.y, s3.y); s3.z = fmaf(v, w3.z, s3.z);
  }
  float imh = imsh[n * 2 + 0], imw = imsh[n * 2 + 1];
  int h = hw / W, w = hw - h * W;
  float acx = ((float)w + 0.5f) * sstride;
  float acy = ((float)h + 0.5f) * sstride;
  float sc[3]  = {s0.x + bsc[0], s0.y + bsc[1], s0.z + bsc[2]};
  float dl[12] = {s0.w + bdl[0], s1.x + bdl[1], s1.y + bdl[2],  s1.z + bdl[3],
                  s1.w + bdl[4], s2.x + bdl[5], s2.y + bdl[6],  s2.z + bdl[7],
                  s2.w + bdl[8], s3.x + bdl[9], s3.y + bdl[10], s3.z + bdl[11]};
  const float srt[3] = {0.70710678118654752440f, 1.0f, 1.41421356237309504880f};
#pragma unroll
  for (int a = 0; a < 3; a++) {
    float aw = asize / srt[a];
    float ah = asize * srt[a];
    float dx = dl[4*a+0], dy = dl[4*a+1];
    float dwv = fminf(dl[4*a+2], BBCLIP);
    float dhv = fminf(dl[4*a+3], BBCLIP);
    float cx = dx * aw + acx;
    float cy = dy * ah + acy;
    float ww = expf(dwv) * aw;
    float hh = expf(dhv) * ah;
    float x1 = cx - 0.5f * ww, y1 = cy - 0.5f * hh;
    float x2 = cx + 0.5f * ww, y2 = cy + 0.5f * hh;
    x1 = fminf(fmaxf(x1, 0.f), imw); x2 = fminf(fmaxf(x2, 0.f), imw);
    y1 = fminf(fmaxf(y1, 0.f), imh); y2 = fminf(fmaxf(y2, 0.f), imh);
    bool ok = (x2 - x1 >= 0.1f) && (y2 - y1 >= 0.1f);
    float s = sc[a];
    float p;
    if (ok) p = (s >= 0.f) ? (1.f / (1.f + expf(-s))) : (expf(s) / (1.f + expf(s)));
    else    p = -1.f;
    int o = n * TOT_PL + lvl_off + hw * 3 + a;
    probs[o] = p;
    *(float4*)&boxes[(size_t)o * 4] = make_float4(x1, y1, x2, y2);
  }
}

// ---------------- K3: grid-parallel radix select over 32-bit float key ----------------
__global__ __launch_bounds__(256) void radix_init(u32* ghist, int2* state) {
  int t = blockIdx.x * 256 + threadIdx.x;
  if (t < 2560) ghist[t] = 0;
  if (t < 10) { state[t].x = 0; state[t].y = c_KK[t % 5]; }
}

__global__ __launch_bounds__(256) void radix_hist(
    const float* __restrict__ probs, u32* __restrict__ ghist,
    const int2* __restrict__ state, int shift)
{
  __shared__ u32 h[256];
  const int t = threadIdx.x;
  const int inst = blockIdx.y;
  const int img = inst / 5, lvl = inst - img * 5;
  const int N = c_LN[lvl], K = c_KK[lvl];
  if (N <= K) return;
  h[t] = 0;
  __syncthreads();
  u64 pref = (u64)(u32)state[inst].x;
  const int base = img * TOT_PL + c_LOFF[lvl];
  const int n4 = N >> 2;
  for (int i4 = blockIdx.x * 256 + t; i4 < n4; i4 += gridDim.x * 256) {
    float4 p4 = *(const float4*)&probs[base + 4 * i4];
    u32 k0 = fkey(p4.x), k1 = fkey(p4.y), k2 = fkey(p4.z), k3 = fkey(p4.w);
    if (((u64)k0 >> (shift + 8)) == pref) atomicAdd(&h[(k0 >> shift) & 255], 1u);
    if (((u64)k1 >> (shift + 8)) == pref) atomicAdd(&h[(k1 >> shift) & 255], 1u);
    if (((u64)k2 >> (shift + 8)) == pref) atomicAdd(&h[(k2 >> shift) & 255], 1u);
    if (((u64)k3 >> (shift + 8)) == pref) atomicAdd(&h[(k3 >> shift) & 255], 1u);
  }
  __syncthreads();
  if (h[t]) atomicAdd(&ghist[inst * 256 + t], h[t]);
}

__global__ __launch_bounds__(256) void radix_pick(u32* __restrict__ ghist, int2* __restrict__ state) {
  const int inst = blockIdx.x;
  const int t = threadIdx.x;
  const int lvl = inst % 5;
  if (c_LN[lvl] <= c_KK[lvl]) return;
  __shared__ int sfx[256];
  __shared__ int sdig, sabove;
  int v = (int)ghist[inst * 256 + t];
  ghist[inst * 256 + t] = 0;
  sfx[t] = v;
  __syncthreads();
  for (int d = 1; d < 256; d <<= 1) {
    int x = (t + d < 256) ? sfx[t + d] : 0;
    __syncthreads();
    sfx[t] += x;
    __syncthreads();
  }
  int remK = state[inst].y;
  int above = (t < 255) ? sfx[t + 1] : 0;
  if (above < remK && sfx[t] >= remK) { sdig = t; sabove = above; }
  __syncthreads();
  if (t == 0) {
    state[inst].x = (int)(((u32)state[inst].x << 8) | (u32)sdig);
    state[inst].y = remK - sabove;
  }
}

__global__ __launch_bounds__(256) void topk_collect(
    const float* __restrict__ probs, const float* __restrict__ boxes,
    const int2* __restrict__ state,
    float* __restrict__ topP, float* __restrict__ topB)
{
  const int t = threadIdx.x;
  const int inst = blockIdx.x;
  const int img = inst / 5, lvl = inst - img * 5;
  const int N = c_LN[lvl], K = c_KK[lvl];
  const int base = img * TOT_PL + c_LOFF[lvl];
  const u32 V = (N <= K) ? 0u : (u32)state[inst].x;

  __shared__ u64 sbuf[2048];
  __shared__ int scnt;
  if (t == 0) scnt = 0;
  __syncthreads();
  const int n4 = N >> 2;
  for (int i4 = t; i4 < n4; i4 += 256) {
    float4 p4 = *(const float4*)&probs[base + 4 * i4];
    float pv[4] = {p4.x, p4.y, p4.z, p4.w};
#pragma unroll
    for (int q = 0; q < 4; q++) {
      u32 k = fkey(pv[q]);
      if (k >= V) {
        int pos = atomicAdd(&scnt, 1);
        if (pos < 2048) sbuf[pos] = ((u64)k << 17) | (u64)(131071 - (4 * i4 + q));
      }
    }
  }
  __syncthreads();
  int cntv = scnt; if (cntv > 2048) cntv = 2048;
  for (int i = t; i < 2048; i += 256) if (i >= cntv) sbuf[i] = 0;
  bitonic_desc<2048>(sbuf, t);
  for (int r = t; r < 1000; r += 256) {
    if (r < K) {
      u64 k = sbuf[r];
      int idx = 131071 - (int)(k & 0x1FFFF);
      topP[inst * 1000 + r] = probs[base + idx];
      *(float4*)&topB[(size_t)(inst * 1000 + r) * 4] = *(const float4*)&boxes[(size_t)(base + idx) * 4];
    } else {
      topP[inst * 1000 + r] = -1.f;
      *(float4*)&topB[(size_t)(inst * 1000 + r) * 4] = make_float4(0, 0, 0, 0);
    }
  }
}

// ---------------- K4a: IoU>thresh bitmask build ----------------
__global__ __launch_bounds__(256) void nms_mask(
    const float* __restrict__ topB, u64* __restrict__ mask)
{
  __shared__ float bx1[1000], by1[1000], bx2[1000], by2[1000], bar[1000];
  const int t = threadIdx.x;
  const int inst = blockIdx.y;
  for (int r = t; r < 1000; r += 256) {
    float4 b = *(const float4*)&topB[(size_t)(inst * 1000 + r) * 4];
    bx1[r] = b.x; by1[r] = b.y; bx2[r] = b.z; by2[r] = b.w;
    bar[r] = (b.z - b.x) * (b.w - b.y);
  }
  __syncthreads();
  const int i = blockIdx.x * 16 + (t >> 4);
  const int w = t & 15;
  if (i >= 1000) return;
  u64 m = 0;
  const int jbase = w * 64;
  if (jbase + 63 > i) {
    float xi1 = bx1[i], yi1 = by1[i], xi2 = bx2[i], yi2 = by2[i], ai = bar[i];
#pragma unroll 4
    for (int b = 0; b < 64; b++) {
      int j = jbase + b;
      if (j > i && j < 1000) {
        float ww = fminf(xi2, bx2[j]) - fmaxf(xi1, bx1[j]); ww = fmaxf(ww, 0.f);
        float hh = fminf(yi2, by2[j]) - fmaxf(yi1, by1[j]); hh = fmaxf(hh, 0.f);
        float inter = ww * hh;
        float iou = inter / (ai + bar[j] - inter + 1e-9f);
        if (iou > 0.7f) m |= 1ull << b;
      }
    }
  }
  mask[(size_t)(inst * 1000 + i) * 16 + w] = m;
}

// ---------------- K4b: sequential suppression scan (1 wave) + ordered compaction ----------------
__global__ __launch_bounds__(256) void nms_scan(
    const float* __restrict__ topP, const float* __restrict__ topB,
    const u64* __restrict__ mask,
    float* __restrict__ perP, float* __restrict__ perB)
{
  const int t = threadIdx.x;
  const int inst = blockIdx.x;
  const int lvl = inst % 5;
  const int K = c_KK[lvl];
  __shared__ float PPl[1000];
  __shared__ u64 SUPL[16];
  __shared__ int scan[256];
  for (int r = t; r < 1000; r += 256) PPl[r] = topP[inst * 1000 + r];
  __syncthreads();

  if (t < 64) {
    const bool ln16 = t < 16;
    const u64* mrow = mask + (size_t)inst * 16000;
    u64 supp = 0;
    u64 buf[16];
#pragma unroll
    for (int d = 0; d < 16; d++) buf[d] = (ln16 && d < K) ? mrow[d * 16 + t] : 0;
    for (int ib = 0; ib < 1000; ib += 16) {
#pragma unroll
      for (int q = 0; q < 16; q++) {
        int i = ib + q;
        if (i < K) {
          u64 sw = __shfl(supp, i >> 6);
          bool sbit = (sw >> (i & 63)) & 1;
          bool keep = (!sbit) && (PPl[i] > 0.f);
          if (keep && ln16) supp |= buf[q];
          int nx = i + 16;
          buf[q] = (ln16 && nx < K) ? mrow[(size_t)nx * 16 + t] : 0;
        }
      }
      if (ib + 16 >= K) break;
    }
    if (ln16) SUPL[t] = supp;
  }
  __syncthreads();

  bool kf[4]; int cntl = 0;
#pragma unroll
  for (int q = 0; q < 4; q++) {
    int r = t * 4 + q;
    bool k = (r < K) && (PPl[r] > 0.f) && !((SUPL[r >> 6] >> (r & 63)) & 1);
    kf[q] = k; cntl += k ? 1 : 0;
  }
  scan[t] = cntl; __syncthreads();
  for (int d = 1; d < 256; d <<= 1) {
    int v = (t >= d) ? scan[t - d] : 0;
    __syncthreads();
    scan[t] += v;
    __syncthreads();
  }
  int pos = (t == 0) ? 0 : scan[t - 1];
  int tot = scan[255];
#pragma unroll
  for (int q = 0; q < 4; q++) {
    int r = t * 4 + q;
    if (r < K && kf[q]) {
      if (pos < 300) {
        perP[inst * 300 + pos] = PPl[r];
        *(float4*)&perB[(size_t)(inst * 300 + pos) * 4] = *(const float4*)&topB[(size_t)(inst * 1000 + r) * 4];
      }
      pos++;
    }
  }
  int start = tot < 300 ? tot : 300;
  for (int r2 = start + t; r2 < 300; r2 += 256) {
    perP[inst * 300 + r2] = -1.f;
    *(float4*)&perB[(size_t)(inst * 300 + r2) * 4] = make_float4(0, 0, 0, 0);
  }
}

// ---------------- K5: global top-300 over 1500, write output + n ----------------
__global__ __launch_bounds__(256) void final_topk(
    const float* __restrict__ perP, const float* __restrict__ perB,
    float* __restrict__ out, float* __restrict__ nout)
{
  const int t = threadIdx.x;
  const int img = blockIdx.x;
  __shared__ u64 sb[2048];
  __shared__ int ncnt;
  for (int i = t; i < 2048; i += 256) {
    u64 k = 0;
    if (i < 1500) k = ((u64)fkey(perP[img * 1500 + i]) << 11) | (u64)(2047 - i);
    sb[i] = k;
  }
  if (t == 0) ncnt = 0;
  bitonic_desc<2048>(sb, t);
  int localn = 0;
  for (int r = t; r < 300; r += 256) {
    u64 k = sb[r];
    int idx = 2047 - (int)(k & 0x7FF);
    float p = perP[img * 1500 + idx];
    bool valid = p > 0.f;
    float4 b = make_float4(0, 0, 0, 0);
    if (valid) b = *(const float4*)&perB[(size_t)(img * 1500 + idx) * 4];
    float* o = out + (size_t)img * 1500 + (size_t)r * 5;
    o[0] = b.x; o[1] = b.y; o[2] = b.z; o[3] = b.w;
    o[4] = valid ? p : 0.f;
    if (valid) localn++;
  }
  atomicAdd(&ncnt, localn);
  __syncthreads();
  if (t == 0) nout[img] = (float)ncnt;
}

// ---------------- launch ----------------
extern "C" void kernel_launch(void* const* d_in, const int* in_sizes, int n_in,
                              void* d_out, int out_size, void* d_ws, size_t ws_size,
                              hipStream_t stream) {
  const float* feats[5] = {(const float*)d_in[0], (const float*)d_in[1], (const float*)d_in[2],
                           (const float*)d_in[3], (const float*)d_in[4]};
  const float* imsh = (const float*)d_in[5];
  const float* Wf   = (const float*)d_in[6];
  const float* bfv  = (const float*)d_in[7];
  const float* Wsc  = (const float*)d_in[8];
  const float* bsc  = (const float*)d_in[9];
  const float* Wdl  = (const float*)d_in[10];
  const float* bdl  = (const float*)d_in[11];

  float* ws     = (float*)d_ws;
  float* rfbuf  = ws;                        // 13,107,200 floats
  float* partial = rfbuf + 4194304;          // overlay in rfbuf tail (small levels only)
  u64*  mask    = (u64*)d_ws;                // overlay: used only after conv/proj done
  float* probs  = rfbuf + 13107200;          // 204,600
  float* boxesb = probs + 204600;            // 818,400
  float* topP   = boxesb + 818400;           // 10,000
  float* topB   = topP + 10000;              // 40,000
  float* perP   = topB + 40000;              // 3,000
  float* perB   = perP + 3000;               // 12,000
  u32*  ghist   = (u32*)(perB + 12000);      // 2,560
  int2* state   = (int2*)(ghist + 2560);     // 10
  u32*  Wt32    = (u32*)(state + 16);        // 884,736 u32

  const int   HSv[5]   = {160, 80, 40, 20, 10};
  const float STRv[5]  = {4.f, 8.f, 16.f, 32.f, 64.f};
  const float SZv[5]   = {32.f, 64.f, 128.f, 256.f, 512.f};
  const int   LOFFv[5] = {0, 76800, 96000, 100800, 102000};
  const int   SPLIT[5] = {1, 2, 4, 8, 16};   // split over 16 ci-blocks

  prep_weights<<<2304, 256, 0, stream>>>(Wf, (unsigned short*)Wt32);

  for (int l = 0; l < 5; l++) {
    int H = HSv[l], W = H, HW = H * W;
    int S = SPLIT[l];
    int fuse = (S == 1) ? 1 : 0;
    int pstride = 2 * 256 * HW;
    int tiles_x = (W + 15) / 16, tiles_y = (H + 7) / 8;
    dim3 g(tiles_x * tiles_y, 2, 2 * S);
    conv_mfma<<<g, 256, 0, stream>>>(feats[l], Wt32, bfv,
                                     fuse ? rfbuf : partial,
                                     H, W, tiles_x, S, pstride, fuse);
    if (!fuse) {
      int E = 2 * 256 * HW;
      reduce_brelu<<<(E + 255) / 256, 256, 0, stream>>>(partial, bfv, rfbuf, E, HW, S, pstride);
    }
    int total = 2 * HW;
    int nb = (total + 255) / 256;
    proj_decode<<<nb, 256, 0, stream>>>(rfbuf, Wsc, bsc, Wdl, bdl, imsh,
                                        probs, boxesb, H, W, LOFFv[l], STRv[l], SZv[l]);
  }
  radix_init<<<10, 256, 0, stream>>>(ghist, state);
  for (int pass = 0; pass < 4; pass++) {
    int shift = 24 - 8 * pass;
    dim3 gh(40, 10);
    radix_hist<<<gh, 256, 0, stream>>>(probs, ghist, state, shift);
    radix_pick<<<10, 256, 0, stream>>>(ghist, state);
  }
  topk_collect<<<10, 256, 0, stream>>>(probs, boxesb, state, topP, topB);
  {
    dim3 gm(63, 10);
    nms_mask<<<gm, 256, 0, stream>>>(topB, mask);
  }
  nms_scan<<<10, 256, 0, stream>>>(topP, topB, mask, perP, perB);
  final_topk<<<2, 256, 0, stream>>>(perP, perB, (float*)d_out, (float*)d_out + 3000);
}

// Round 6
// 1392.658 us; speedup vs baseline: 3.0940x; 3.0940x over previous
//
#include <hip/hip_runtime.h>
#include <stdint.h>

typedef unsigned long long u64;
typedef unsigned int u32;
using short8  = __attribute__((ext_vector_type(8))) short;
using f32x16  = __attribute__((ext_vector_type(16))) float;

__constant__ int c_LN[5]   = {76800, 19200, 4800, 1200, 300}; // H*H*3 per level
__constant__ int c_LOFF[5] = {0, 76800, 96000, 100800, 102000};
__constant__ int c_KK[5]   = {1000, 1000, 1000, 1000, 300};   // k1 = min(1000, N)

#define TOT_PL 102300
#define BBCLIP 4.1351665567423560f

__device__ __forceinline__ u32 fkey(float f) {
  u32 b = __float_as_uint(f);
  return b ^ (u32)(((int)b >> 31) | 0x80000000u);
}

template<int NELEM>
__device__ __forceinline__ void bitonic_desc(u64* sb, int t) {
  constexpr int PAIRS = NELEM / 2;
  for (int size = 2; size <= NELEM; size <<= 1) {
    for (int stride = size >> 1; stride > 0; stride >>= 1) {
      __syncthreads();
      for (int i = t; i < PAIRS; i += 256) {
        int pos = 2 * i - (i & (stride - 1));
        u64 a = sb[pos], b = sb[pos + stride];
        bool desc = ((pos & size) == 0);
        if (desc ? (a < b) : (a > b)) { sb[pos] = b; sb[pos + stride] = a; }
      }
    }
  }
  __syncthreads();
}

// ---------------- K0: pre-transpose weights, 3-way bf16 split ----------------
// chunk ca = tap*16 + g covers k [16ca,16ca+16): ci = g*16 + kloc, kloc = half*8 + j.
// Wt u16 layout: slice = (ca*6 + split*2 + half); within slice: co granule of 8 u16.
__global__ __launch_bounds__(256) void prep_weights(
    const float* __restrict__ Wf, unsigned short* __restrict__ Wt)
{
  int idx = blockIdx.x * 256 + threadIdx.x;   // E = 2304*256
  if (idx >= 589824) return;
  int co = idx & 255;
  int k2 = idx >> 8;            // 0..2303
  int chunk = k2 >> 4, kloc = k2 & 15;
  int tap = chunk / 16, g = chunk & 15;
  int ci = (g << 4) + kloc;
  float v = Wf[co * 2304 + ci * 9 + tap];
  u32 u0 = __float_as_uint(v) & 0xFFFF0000u;
  float r1 = v - __uint_as_float(u0);
  u32 u1 = __float_as_uint(r1) & 0xFFFF0000u;
  float r2 = r1 - __uint_as_float(u1);
  u32 u2 = __float_as_uint(r2) & 0xFFFF0000u;
  int half = kloc >> 3, j = kloc & 7;
  int base = (chunk * 6 + half) * 2048 + co * 8 + j;   // +4096 u16 per split
  Wt[base]          = (unsigned short)(u0 >> 16);
  Wt[base + 4096]   = (unsigned short)(u1 >> 16);
  Wt[base + 8192]   = (unsigned short)(u2 >> 16);
}

// ---------------- K1: 3x3 conv via MFMA, halo-staged, split-once, LDS-A ----------------
// tile 128co x 128px (8 rows x 16 cols), 4 waves 2x2 of 64x64.
// haloP u32 layout: [plane = sp*2+half][pos = y*20+x (200)][pair pp (4)]  -> B-frag = one ds_read_b128.
// Abuf: per-tap 12KB staged copy of Wt chunk (768 uint4 granules).
__global__ __launch_bounds__(256, 3) void conv_mfma(
    const float* __restrict__ feat, const u32* __restrict__ Wt32,
    const float* __restrict__ bf, float* __restrict__ out0,
    int H, int W, int tiles_x, int S, int pstride, int fuse)
{
  __shared__ u32  haloP[4800];     // 19.2 KB
  __shared__ uint4 Abuf[768];      // 12.3 KB
  const int t  = threadIdx.x;
  const int HW = H * W;
  const int tile = blockIdx.x;
  const int tx = tile % tiles_x, ty = tile / tiles_x;
  const int c0 = tx * 16, r0 = ty * 8;
  const int cob = blockIdx.y * 128;
  const int bz = blockIdx.z;
  const int n = bz / S, s = bz - n * S;
  const int gcount = 16 / S, g0 = s * gcount;
  const float* featN = feat + (size_t)n * 256 * HW;
  const uint4* Wtq = (const uint4*)Wt32;

  const int lane = t & 63;
  const int wave = t >> 6;
  const int wy = wave >> 1, wx = wave & 1;
  const int fh = lane >> 5;          // frag k-half
  const int ln31 = lane & 31;

  // precompute staging decomposition for this thread's 7 halo elements
  f32x16 acc[2][2];
#pragma unroll
  for (int i = 0; i < 2; i++)
#pragma unroll
    for (int j = 0; j < 2; j++)
#pragma unroll
      for (int e = 0; e < 16; e++) acc[i][j][e] = 0.f;

  for (int gl = 0; gl < gcount; gl++) {
    const int g = g0 + gl;
    for (int tap = 0; tap < 9; tap++) {
      __syncthreads();   // protect haloP (tap0) / Abuf from previous readers
      if (tap == 0) {
        // ---- stage halo: global fp32 -> 3-way bf16 split -> pair-packed LDS ----
#pragma unroll
        for (int i = 0; i < 7; i++) {
          int e2 = t + i * 256;
          if (e2 < 1600) {
            int pp = e2 & 3, q = e2 >> 2;          // q in [0,400)
            int half = q / 200, rem = q - half * 200;
            int y = rem / 20, x = rem - y * 20;
            int gy = r0 + y - 1, gx = c0 + x - 1;
            bool val = (x < 18) && ((unsigned)gy < (unsigned)H) && ((unsigned)gx < (unsigned)W);
            int ci0 = half * 8 + pp * 2;
            const float* fc = featN + (size_t)((g << 4) + ci0) * HW;
            int off = val ? (gy * W + gx) : 0;
            float a = val ? fc[off] : 0.f;
            float b = val ? fc[off + HW] : 0.f;
            u32 a0 = __float_as_uint(a) & 0xFFFF0000u;
            float ar1 = a - __uint_as_float(a0);
            u32 a1 = __float_as_uint(ar1) & 0xFFFF0000u;
            float ar2 = ar1 - __uint_as_float(a1);
            u32 a2 = __float_as_uint(ar2) & 0xFFFF0000u;
            u32 b0 = __float_as_uint(b) & 0xFFFF0000u;
            float br1 = b - __uint_as_float(b0);
            u32 b1 = __float_as_uint(br1) & 0xFFFF0000u;
            float br2 = br1 - __uint_as_float(b1);
            u32 b2 = __float_as_uint(br2) & 0xFFFF0000u;
            int o = half * 800 + rem * 4 + pp;
            haloP[o]        = (a0 >> 16) | b0;
            haloP[o + 1600] = (a1 >> 16) | b1;
            haloP[o + 3200] = (a2 >> 16) | b2;
          }
        }
      }
      // ---- stage A chunk (pure copy, coalesced; Wt is L2-resident) ----
      {
        const int ca = tap * 16 + g;
#pragma unroll
        for (int q2 = 0; q2 < 3; q2++) {
          int g2 = t + q2 * 256;
          int slice = g2 >> 7, co_loc = g2 & 127;
          Abuf[g2] = Wtq[(size_t)(ca * 6 + slice) * 256 + cob + co_loc];
        }
      }
      __syncthreads();
      // ---- fragment loads: direct LDS wide reads (no local assembly) ----
      const int tdy = tap / 3, tdx = tap - tdy * 3;
      short8 aT[3][2], bT[3][2];
#pragma unroll
      for (int sp = 0; sp < 3; sp++) {
#pragma unroll
        for (int ti = 0; ti < 2; ti++)
          aT[sp][ti] = *(const short8*)&Abuf[(sp * 2 + fh) * 128 + wy * 64 + ti * 32 + ln31];
#pragma unroll
        for (int tj = 0; tj < 2; tj++) {
          int px = wx * 64 + tj * 32 + ln31;
          int pos = ((px >> 4) + tdy) * 20 + (px & 15) + tdx;
          bT[sp][tj] = *(const short8*)&haloP[(sp * 2 + fh) * 800 + pos * 4];
        }
      }
      // ---- 6 split-products, smallest first ----
#pragma unroll
      for (int ti = 0; ti < 2; ti++)
#pragma unroll
        for (int tj = 0; tj < 2; tj++) {
          acc[ti][tj] = __builtin_amdgcn_mfma_f32_32x32x16_bf16(aT[1][ti], bT[1][tj], acc[ti][tj], 0, 0, 0);
          acc[ti][tj] = __builtin_amdgcn_mfma_f32_32x32x16_bf16(aT[0][ti], bT[2][tj], acc[ti][tj], 0, 0, 0);
          acc[ti][tj] = __builtin_amdgcn_mfma_f32_32x32x16_bf16(aT[2][ti], bT[0][tj], acc[ti][tj], 0, 0, 0);
          acc[ti][tj] = __builtin_amdgcn_mfma_f32_32x32x16_bf16(aT[0][ti], bT[1][tj], acc[ti][tj], 0, 0, 0);
          acc[ti][tj] = __builtin_amdgcn_mfma_f32_32x32x16_bf16(aT[1][ti], bT[0][tj], acc[ti][tj], 0, 0, 0);
          acc[ti][tj] = __builtin_amdgcn_mfma_f32_32x32x16_bf16(aT[0][ti], bT[0][tj], acc[ti][tj], 0, 0, 0);
        }
    }
  }

  // ---- epilogue ----
  float* outp = fuse ? out0 : (out0 + (size_t)s * pstride);
#pragma unroll
  for (int ti = 0; ti < 2; ti++)
#pragma unroll
    for (int tj = 0; tj < 2; tj++) {
      int pxo = wx * 64 + tj * 32 + ln31;
      int y = r0 + (pxo >> 4), x = c0 + (pxo & 15);
      if (y >= H || x >= W) continue;
#pragma unroll
      for (int reg = 0; reg < 16; reg++) {
        int row = (reg & 3) + 8 * (reg >> 2) + 4 * fh;
        int co = cob + wy * 64 + ti * 32 + row;
        float vv = acc[ti][tj][reg];
        if (fuse) vv = fmaxf(vv + bf[co], 0.f);
        outp[(size_t)(n * 256 + co) * HW + y * W + x] = vv;
      }
    }
}

// ---------------- K1b: sum split-K partials + bias + relu (deterministic order) ----------------
__global__ __launch_bounds__(256) void reduce_brelu(
    const float* __restrict__ partial, const float* __restrict__ bf,
    float* __restrict__ rf, int E, int HW, int S, int pstride)
{
  int idx = blockIdx.x * 256 + threadIdx.x;
  if (idx >= E) return;
  float sum = partial[idx];
  for (int sp = 1; sp < S; sp++) sum += partial[(size_t)sp * pstride + idx];
  int c = (idx / HW) & 255;
  rf[idx] = fmaxf(sum + bf[c], 0.f);
}

// ---------------- K2: 15-ch projection + sigmoid + decode + clip + filter ----------------
__global__ __launch_bounds__(256) void proj_decode(
    const float* __restrict__ rf, const float* __restrict__ Wsc,
    const float* __restrict__ bsc, const float* __restrict__ Wdl,
    const float* __restrict__ bdl, const float* __restrict__ imsh,
    float* __restrict__ probs, float* __restrict__ boxes,
    int H, int W, int lvl_off, float sstride, float asize)
{
  __shared__ float4 wall[256 * 4];
  const int t = threadIdx.x;
  {
    int c = t;
    wall[c * 4 + 0] = make_float4(Wsc[c], Wsc[256 + c], Wsc[512 + c], Wdl[c]);
    wall[c * 4 + 1] = make_float4(Wdl[256 + c], Wdl[512 + c], Wdl[768 + c], Wdl[1024 + c]);
    wall[c * 4 + 2] = make_float4(Wdl[1280 + c], Wdl[1536 + c], Wdl[1792 + c], Wdl[2048 + c]);
    wall[c * 4 + 3] = make_float4(Wdl[2304 + c], Wdl[2560 + c], Wdl[2816 + c], 0.f);
  }
  __syncthreads();
  const int HW = H * W;
  int idx = blockIdx.x * 256 + t;
  if (idx >= 2 * HW) return;
  int n  = idx / HW;
  int hw = idx - n * HW;
  const float* rp = rf + (size_t)n * 256 * HW + hw;
  float4 s0 = {0,0,0,0}, s1 = {0,0,0,0}, s2 = {0,0,0,0}, s3 = {0,0,0,0};
#pragma unroll 4
  for (int c = 0; c < 256; c++) {
    float v = rp[(size_t)c * HW];
    float4 w0 = wall[c*4+0], w1 = wall[c*4+1], w2 = wall[c*4+2], w3 = wall[c*4+3];
    s0.x = fmaf(v, w0.x, s0.x); s0.y = fmaf(v, w0.y, s0.y); s0.z = fmaf(v, w0.z, s0.z); s0.w = fmaf(v, w0.w, s0.w);
    s1.x = fmaf(v, w1.x, s1.x); s1.y = fmaf(v, w1.y, s1.y); s1.z = fmaf(v, w1.z, s1.z); s1.w = fmaf(v, w1.w, s1.w);
    s2.x = fmaf(v, w2.x, s2.x); s2.y = fmaf(v, w2.y, s2.y); s2.z = fmaf(v, w2.z, s2.z); s2.w = fmaf(v, w2.w, s2.w);
    s3.x = fmaf(v, w3.x, s3.x); s3.y = fmaf(v, w3.y, s3.y); s3.z = fmaf(v, w3.z, s3.z);
  }
  float imh = imsh[n * 2 + 0], imw = imsh[n * 2 + 1];
  int h = hw / W, w = hw - h * W;
  float acx = ((float)w + 0.5f) * sstride;
  float acy = ((float)h + 0.5f) * sstride;
  float sc[3]  = {s0.x + bsc[0], s0.y + bsc[1], s0.z + bsc[2]};
  float dl[12] = {s0.w + bdl[0], s1.x + bdl[1], s1.y + bdl[2],  s1.z + bdl[3],
                  s1.w + bdl[4], s2.x + bdl[5], s2.y + bdl[6],  s2.z + bdl[7],
                  s2.w + bdl[8], s3.x + bdl[9], s3.y + bdl[10], s3.z + bdl[11]};
  const float srt[3] = {0.70710678118654752440f, 1.0f, 1.41421356237309504880f};
#pragma unroll
  for (int a = 0; a < 3; a++) {
    float aw = asize / srt[a];
    float ah = asize * srt[a];
    float dx = dl[4*a+0], dy = dl[4*a+1];
    float dwv = fminf(dl[4*a+2], BBCLIP);
    float dhv = fminf(dl[4*a+3], BBCLIP);
    float cx = dx * aw + acx;
    float cy = dy * ah + acy;
    float ww = expf(dwv) * aw;
    float hh = expf(dhv) * ah;
    float x1 = cx - 0.5f * ww, y1 = cy - 0.5f * hh;
    float x2 = cx + 0.5f * ww, y2 = cy + 0.5f * hh;
    x1 = fminf(fmaxf(x1, 0.f), imw); x2 = fminf(fmaxf(x2, 0.f), imw);
    y1 = fminf(fmaxf(y1, 0.f), imh); y2 = fminf(fmaxf(y2, 0.f), imh);
    bool ok = (x2 - x1 >= 0.1f) && (y2 - y1 >= 0.1f);
    float s = sc[a];
    float p;
    if (ok) p = (s >= 0.f) ? (1.f / (1.f + expf(-s))) : (expf(s) / (1.f + expf(s)));
    else    p = -1.f;
    int o = n * TOT_PL + lvl_off + hw * 3 + a;
    probs[o] = p;
    *(float4*)&boxes[(size_t)o * 4] = make_float4(x1, y1, x2, y2);
  }
}

// ---------------- K3: grid-parallel radix select over 32-bit float key ----------------
__global__ __launch_bounds__(256) void radix_init(u32* ghist, int2* state) {
  int t = blockIdx.x * 256 + threadIdx.x;
  if (t < 2560) ghist[t] = 0;
  if (t < 10) { state[t].x = 0; state[t].y = c_KK[t % 5]; }
}

__global__ __launch_bounds__(256) void radix_hist(
    const float* __restrict__ probs, u32* __restrict__ ghist,
    const int2* __restrict__ state, int shift)
{
  __shared__ u32 h[256];
  const int t = threadIdx.x;
  const int inst = blockIdx.y;
  const int img = inst / 5, lvl = inst - img * 5;
  const int N = c_LN[lvl], K = c_KK[lvl];
  if (N <= K) return;
  h[t] = 0;
  __syncthreads();
  u64 pref = (u64)(u32)state[inst].x;
  const int base = img * TOT_PL + c_LOFF[lvl];
  const int n4 = N >> 2;
  for (int i4 = blockIdx.x * 256 + t; i4 < n4; i4 += gridDim.x * 256) {
    float4 p4 = *(const float4*)&probs[base + 4 * i4];
    u32 k0 = fkey(p4.x), k1 = fkey(p4.y), k2 = fkey(p4.z), k3 = fkey(p4.w);
    if (((u64)k0 >> (shift + 8)) == pref) atomicAdd(&h[(k0 >> shift) & 255], 1u);
    if (((u64)k1 >> (shift + 8)) == pref) atomicAdd(&h[(k1 >> shift) & 255], 1u);
    if (((u64)k2 >> (shift + 8)) == pref) atomicAdd(&h[(k2 >> shift) & 255], 1u);
    if (((u64)k3 >> (shift + 8)) == pref) atomicAdd(&h[(k3 >> shift) & 255], 1u);
  }
  __syncthreads();
  if (h[t]) atomicAdd(&ghist[inst * 256 + t], h[t]);
}

__global__ __launch_bounds__(256) void radix_pick(u32* __restrict__ ghist, int2* __restrict__ state) {
  const int inst = blockIdx.x;
  const int t = threadIdx.x;
  const int lvl = inst % 5;
  if (c_LN[lvl] <= c_KK[lvl]) return;
  __shared__ int sfx[256];
  __shared__ int sdig, sabove;
  int v = (int)ghist[inst * 256 + t];
  ghist[inst * 256 + t] = 0;
  sfx[t] = v;
  __syncthreads();
  for (int d = 1; d < 256; d <<= 1) {
    int x = (t + d < 256) ? sfx[t + d] : 0;
    __syncthreads();
    sfx[t] += x;
    __syncthreads();
  }
  int remK = state[inst].y;
  int above = (t < 255) ? sfx[t + 1] : 0;
  if (above < remK && sfx[t] >= remK) { sdig = t; sabove = above; }
  __syncthreads();
  if (t == 0) {
    state[inst].x = (int)(((u32)state[inst].x << 8) | (u32)sdig);
    state[inst].y = remK - sabove;
  }
}

__global__ __launch_bounds__(256) void topk_collect(
    const float* __restrict__ probs, const float* __restrict__ boxes,
    const int2* __restrict__ state,
    float* __restrict__ topP, float* __restrict__ topB)
{
  const int t = threadIdx.x;
  const int inst = blockIdx.x;
  const int img = inst / 5, lvl = inst - img * 5;
  const int N = c_LN[lvl], K = c_KK[lvl];
  const int base = img * TOT_PL + c_LOFF[lvl];
  const u32 V = (N <= K) ? 0u : (u32)state[inst].x;

  __shared__ u64 sbuf[2048];
  __shared__ int scnt;
  if (t == 0) scnt = 0;
  __syncthreads();
  const int n4 = N >> 2;
  for (int i4 = t; i4 < n4; i4 += 256) {
    float4 p4 = *(const float4*)&probs[base + 4 * i4];
    float pv[4] = {p4.x, p4.y, p4.z, p4.w};
#pragma unroll
    for (int q = 0; q < 4; q++) {
      u32 k = fkey(pv[q]);
      if (k >= V) {
        int pos = atomicAdd(&scnt, 1);
        if (pos < 2048) sbuf[pos] = ((u64)k << 17) | (u64)(131071 - (4 * i4 + q));
      }
    }
  }
  __syncthreads();
  int cntv = scnt; if (cntv > 2048) cntv = 2048;
  for (int i = t; i < 2048; i += 256) if (i >= cntv) sbuf[i] = 0;
  bitonic_desc<2048>(sbuf, t);
  for (int r = t; r < 1000; r += 256) {
    if (r < K) {
      u64 k = sbuf[r];
      int idx = 131071 - (int)(k & 0x1FFFF);
      topP[inst * 1000 + r] = probs[base + idx];
      *(float4*)&topB[(size_t)(inst * 1000 + r) * 4] = *(const float4*)&boxes[(size_t)(base + idx) * 4];
    } else {
      topP[inst * 1000 + r] = -1.f;
      *(float4*)&topB[(size_t)(inst * 1000 + r) * 4] = make_float4(0, 0, 0, 0);
    }
  }
}

// ---------------- K4a: IoU>thresh bitmask build ----------------
__global__ __launch_bounds__(256) void nms_mask(
    const float* __restrict__ topB, u64* __restrict__ mask)
{
  __shared__ float bx1[1000], by1[1000], bx2[1000], by2[1000], bar[1000];
  const int t = threadIdx.x;
  const int inst = blockIdx.y;
  for (int r = t; r < 1000; r += 256) {
    float4 b = *(const float4*)&topB[(size_t)(inst * 1000 + r) * 4];
    bx1[r] = b.x; by1[r] = b.y; bx2[r] = b.z; by2[r] = b.w;
    bar[r] = (b.z - b.x) * (b.w - b.y);
  }
  __syncthreads();
  const int i = blockIdx.x * 16 + (t >> 4);
  const int w = t & 15;
  if (i >= 1000) return;
  u64 m = 0;
  const int jbase = w * 64;
  if (jbase + 63 > i) {
    float xi1 = bx1[i], yi1 = by1[i], xi2 = bx2[i], yi2 = by2[i], ai = bar[i];
#pragma unroll 4
    for (int b = 0; b < 64; b++) {
      int j = jbase + b;
      if (j > i && j < 1000) {
        float ww = fminf(xi2, bx2[j]) - fmaxf(xi1, bx1[j]); ww = fmaxf(ww, 0.f);
        float hh = fminf(yi2, by2[j]) - fmaxf(yi1, by1[j]); hh = fmaxf(hh, 0.f);
        float inter = ww * hh;
        float iou = inter / (ai + bar[j] - inter + 1e-9f);
        if (iou > 0.7f) m |= 1ull << b;
      }
    }
  }
  mask[(size_t)(inst * 1000 + i) * 16 + w] = m;
}

// ---------------- K4b: sequential suppression scan (1 wave) + ordered compaction ----------------
__global__ __launch_bounds__(256) void nms_scan(
    const float* __restrict__ topP, const float* __restrict__ topB,
    const u64* __restrict__ mask,
    float* __restrict__ perP, float* __restrict__ perB)
{
  const int t = threadIdx.x;
  const int inst = blockIdx.x;
  const int lvl = inst % 5;
  const int K = c_KK[lvl];
  __shared__ float PPl[1000];
  __shared__ u64 SUPL[16];
  __shared__ int scan[256];
  for (int r = t; r < 1000; r += 256) PPl[r] = topP[inst * 1000 + r];
  __syncthreads();

  if (t < 64) {
    const bool ln16 = t < 16;
    const u64* mrow = mask + (size_t)inst * 16000;
    u64 supp = 0;
    u64 buf[16];
#pragma unroll
    for (int d = 0; d < 16; d++) buf[d] = (ln16 && d < K) ? mrow[d * 16 + t] : 0;
    for (int ib = 0; ib < 1000; ib += 16) {
#pragma unroll
      for (int q = 0; q < 16; q++) {
        int i = ib + q;
        if (i < K) {
          u64 sw = __shfl(supp, i >> 6);
          bool sbit = (sw >> (i & 63)) & 1;
          bool keep = (!sbit) && (PPl[i] > 0.f);
          if (keep && ln16) supp |= buf[q];
          int nx = i + 16;
          buf[q] = (ln16 && nx < K) ? mrow[(size_t)nx * 16 + t] : 0;
        }
      }
      if (ib + 16 >= K) break;
    }
    if (ln16) SUPL[t] = supp;
  }
  __syncthreads();

  bool kf[4]; int cntl = 0;
#pragma unroll
  for (int q = 0; q < 4; q++) {
    int r = t * 4 + q;
    bool k = (r < K) && (PPl[r] > 0.f) && !((SUPL[r >> 6] >> (r & 63)) & 1);
    kf[q] = k; cntl += k ? 1 : 0;
  }
  scan[t] = cntl; __syncthreads();
  for (int d = 1; d < 256; d <<= 1) {
    int v = (t >= d) ? scan[t - d] : 0;
    __syncthreads();
    scan[t] += v;
    __syncthreads();
  }
  int pos = (t == 0) ? 0 : scan[t - 1];
  int tot = scan[255];
#pragma unroll
  for (int q = 0; q < 4; q++) {
    int r = t * 4 + q;
    if (r < K && kf[q]) {
      if (pos < 300) {
        perP[inst * 300 + pos] = PPl[r];
        *(float4*)&perB[(size_t)(inst * 300 + pos) * 4] = *(const float4*)&topB[(size_t)(inst * 1000 + r) * 4];
      }
      pos++;
    }
  }
  int start = tot < 300 ? tot : 300;
  for (int r2 = start + t; r2 < 300; r2 += 256) {
    perP[inst * 300 + r2] = -1.f;
    *(float4*)&perB[(size_t)(inst * 300 + r2) * 4] = make_float4(0, 0, 0, 0);
  }
}

// ---------------- K5: global top-300 over 1500, write output + n ----------------
__global__ __launch_bounds__(256) void final_topk(
    const float* __restrict__ perP, const float* __restrict__ perB,
    float* __restrict__ out, float* __restrict__ nout)
{
  const int t = threadIdx.x;
  const int img = blockIdx.x;
  __shared__ u64 sb[2048];
  __shared__ int ncnt;
  for (int i = t; i < 2048; i += 256) {
    u64 k = 0;
    if (i < 1500) k = ((u64)fkey(perP[img * 1500 + i]) << 11) | (u64)(2047 - i);
    sb[i] = k;
  }
  if (t == 0) ncnt = 0;
  bitonic_desc<2048>(sb, t);
  int localn = 0;
  for (int r = t; r < 300; r += 256) {
    u64 k = sb[r];
    int idx = 2047 - (int)(k & 0x7FF);
    float p = perP[img * 1500 + idx];
    bool valid = p > 0.f;
    float4 b = make_float4(0, 0, 0, 0);
    if (valid) b = *(const float4*)&perB[(size_t)(img * 1500 + idx) * 4];
    float* o = out + (size_t)img * 1500 + (size_t)r * 5;
    o[0] = b.x; o[1] = b.y; o[2] = b.z; o[3] = b.w;
    o[4] = valid ? p : 0.f;
    if (valid) localn++;
  }
  atomicAdd(&ncnt, localn);
  __syncthreads();
  if (t == 0) nout[img] = (float)ncnt;
}

// ---------------- launch ----------------
extern "C" void kernel_launch(void* const* d_in, const int* in_sizes, int n_in,
                              void* d_out, int out_size, void* d_ws, size_t ws_size,
                              hipStream_t stream) {
  const float* feats[5] = {(const float*)d_in[0], (const float*)d_in[1], (const float*)d_in[2],
                           (const float*)d_in[3], (const float*)d_in[4]};
  const float* imsh = (const float*)d_in[5];
  const float* Wf   = (const float*)d_in[6];
  const float* bfv  = (const float*)d_in[7];
  const float* Wsc  = (const float*)d_in[8];
  const float* bsc  = (const float*)d_in[9];
  const float* Wdl  = (const float*)d_in[10];
  const float* bdl  = (const float*)d_in[11];

  float* ws     = (float*)d_ws;
  float* rfbuf  = ws;                        // 13,107,200 floats
  float* partial = rfbuf + 4194304;          // overlay in rfbuf tail (small levels only)
  u64*  mask    = (u64*)d_ws;                // overlay: used only after conv/proj done
  float* probs  = rfbuf + 13107200;          // 204,600
  float* boxesb = probs + 204600;            // 818,400
  float* topP   = boxesb + 818400;           // 10,000
  float* topB   = topP + 10000;              // 40,000
  float* perP   = topB + 40000;              // 3,000
  float* perB   = perP + 3000;               // 12,000
  u32*  ghist   = (u32*)(perB + 12000);      // 2,560
  int2* state   = (int2*)(ghist + 2560);     // 10
  u32*  Wt32    = (u32*)(state + 16);        // 884,736 u32

  const int   HSv[5]   = {160, 80, 40, 20, 10};
  const float STRv[5]  = {4.f, 8.f, 16.f, 32.f, 64.f};
  const float SZv[5]   = {32.f, 64.f, 128.f, 256.f, 512.f};
  const int   LOFFv[5] = {0, 76800, 96000, 100800, 102000};
  const int   SPLIT[5] = {1, 2, 4, 8, 16};   // split over 16 ci-blocks

  prep_weights<<<2304, 256, 0, stream>>>(Wf, (unsigned short*)Wt32);

  for (int l = 0; l < 5; l++) {
    int H = HSv[l], W = H, HW = H * W;
    int S = SPLIT[l];
    int fuse = (S == 1) ? 1 : 0;
    int pstride = 2 * 256 * HW;
    int tiles_x = (W + 15) / 16, tiles_y = (H + 7) / 8;
    dim3 g(tiles_x * tiles_y, 2, 2 * S);
    conv_mfma<<<g, 256, 0, stream>>>(feats[l], Wt32, bfv,
                                     fuse ? rfbuf : partial,
                                     H, W, tiles_x, S, pstride, fuse);
    if (!fuse) {
      int E = 2 * 256 * HW;
      reduce_brelu<<<(E + 255) / 256, 256, 0, stream>>>(partial, bfv, rfbuf, E, HW, S, pstride);
    }
    int total = 2 * HW;
    int nb = (total + 255) / 256;
    proj_decode<<<nb, 256, 0, stream>>>(rfbuf, Wsc, bsc, Wdl, bdl, imsh,
                                        probs, boxesb, H, W, LOFFv[l], STRv[l], SZv[l]);
  }
  radix_init<<<10, 256, 0, stream>>>(ghist, state);
  for (int pass = 0; pass < 4; pass++) {
    int shift = 24 - 8 * pass;
    dim3 gh(40, 10);
    radix_hist<<<gh, 256, 0, stream>>>(probs, ghist, state, shift);
    radix_pick<<<10, 256, 0, stream>>>(ghist, state);
  }
  topk_collect<<<10, 256, 0, stream>>>(probs, boxesb, state, topP, topB);
  {
    dim3 gm(63, 10);
    nms_mask<<<gm, 256, 0, stream>>>(topB, mask);
  }
  nms_scan<<<10, 256, 0, stream>>>(topP, topB, mask, perP, perB);
  final_topk<<<2, 256, 0, stream>>>(perP, perB, (float*)d_out, (float*)d_out + 3000);
}